// Round 10
// baseline (200.183 us; speedup 1.0000x reference)
//
#include <hip/hip_runtime.h>
#include <math.h>

#define BB   4096
#define KK   200
#define DD   128
#define FDIM 1024
#define MASK_FILL (-4294967295.0f)   // -(2^32)+1, as fp32

typedef float fx4 __attribute__((ext_vector_type(4)));

// ---------------- Kernel 1: target = target_feats @ W^T  ([B,FD] x [D,FD] -> [B,D])
// 512 blocks x 512 threads; 8 batch rows per block; FD split in QUARTERS per
// thread (h = tid>>7 in 0..3) -> 16 waves/CU to hide the W-load L2 latency.
__global__ __launch_bounds__(512) void target_gemm(const float* __restrict__ tf,
                                                   const float* __restrict__ W,
                                                   float* __restrict__ tgt) {
    __shared__ float s_tf[8 * FDIM];        // 32 KiB
    __shared__ float s_red[8][4][DD];       // 16 KiB: per-h partials
    const int tid = threadIdx.x;
    const int d   = tid & 127;
    const int h   = tid >> 7;               // 0..3: which quarter of FD (wave-uniform)
    const size_t r0 = (size_t)blockIdx.x * 8;

    const fx4* src = (const fx4*)(tf + r0 * FDIM);
    for (int i = tid; i < 8 * FDIM / 4; i += 512)
        ((fx4*)s_tf)[i] = src[i];
    __syncthreads();

    float acc[8] = {0, 0, 0, 0, 0, 0, 0, 0};
    const fx4* wr = (const fx4*)(W + (size_t)d * FDIM) + h * (FDIM / 16);
    #pragma unroll 4
    for (int i = 0; i < FDIM / 16; ++i) {   // 64 fx4 chunks of this quarter
        fx4 w = wr[i];
        #pragma unroll
        for (int r = 0; r < 8; ++r) {
            fx4 t = ((const fx4*)(s_tf + r * FDIM + h * (FDIM / 4)))[i];  // wave-broadcast
            acc[r] += w.x * t.x + w.y * t.y + w.z * t.z + w.w * t.w;
        }
    }
    #pragma unroll
    for (int r = 0; r < 8; ++r) s_red[r][h][d] = acc[r];
    __syncthreads();
    if (h == 0) {
        #pragma unroll
        for (int r = 0; r < 8; ++r)
            tgt[(r0 + r) * DD + d] = s_red[r][0][d] + s_red[r][1][d]
                                   + s_red[r][2][d] + s_red[r][3][d];
    }
}

// ---------------- Kernel 2: TWO waves per batch row (k 0..99 / 100..199), one
// pass, online softmax. Within a wave: lanes 0-31 even k, lanes 32-63 odd k.
// Chunks of 2 row-pairs (4 loads in flight) keep VGPR <= 64 so 8 waves/SIMD
// (32 waves/CU) hide HBM latency. One LDS merge + single barrier at the end.
__global__ __launch_bounds__(256, 8) void attn_online(const float* __restrict__ nf,
                                                      const float* __restrict__ nl,
                                                      const int*   __restrict__ mask,
                                                      const float* __restrict__ tgt,
                                                      float* __restrict__ out) {
    __shared__ float s_m[2][2], s_s[2][2];
    __shared__ fx4   s_an[2][2][32];     // [bloc][w][col]
    __shared__ fx4   s_al[2][2][32];

    const int tid  = threadIdx.x;
    const int lane = tid & 63;
    const int l32  = lane & 31;          // fx4 column (d = 4*l32)
    const int h    = (lane >> 5) & 1;    // parity half: 0 -> even k, 1 -> odd k
    const int bloc = tid >> 7;           // which of the block's 2 batch rows
    const int b    = __builtin_amdgcn_readfirstlane(blockIdx.x * 2 + bloc);
    const int w    = __builtin_amdgcn_readfirstlane((tid >> 6) & 1);  // k-range half

    const fx4* nf4 = (const fx4*)(nf + (size_t)b * KK * DD) + (size_t)w * 50 * 64;
    const fx4* nl4 = (const fx4*)(nl + (size_t)b * KK * DD) + (size_t)w * 50 * 64;
    const int* mb  = mask + (size_t)b * KK + w * 100;
    const fx4  tg  = ((const fx4*)(tgt + (size_t)b * DD))[l32];

    float m = -INFINITY, s = 0.0f;
    fx4 an = {0, 0, 0, 0}, al = {0, 0, 0, 0};

    for (int c = 0; c < 25; ++c) {       // 25 chunks x 2 pairs (4 k) per wave
        fx4 vn[2], vl[2];
        #pragma unroll
        for (int j = 0; j < 2; ++j) {
            const int idx = (c * 2 + j) * 64 + lane;   // rows 4c+2j+h, col l32
            vn[j] = nf4[idx];
            vl[j] = nl4[idx];
        }
        float a[2];
        #pragma unroll
        for (int j = 0; j < 2; ++j) {
            float d = vn[j].x * tg.x + vn[j].y * tg.y + vn[j].z * tg.z + vn[j].w * tg.w;
            #pragma unroll
            for (int off = 16; off > 0; off >>= 1)   // stays within 32-lane halves
                d += __shfl_xor(d, off);
            const int k0 = c * 4 + 2 * j;
            const int mk = h ? mb[k0 + 1] : mb[k0];  // scalar loads, vector select
            a[j] = (mk > 0) ? d : MASK_FILL;
        }
        const float mn = fmaxf(m, fmaxf(a[0], a[1]));
        const float r  = __expf(m - mn);             // exp(-inf)=0 on first chunk
        m = mn;
        s *= r; an *= r; al *= r;
        #pragma unroll
        for (int j = 0; j < 2; ++j) {
            const float p = __expf(a[j] - m);        // p <= 1 always
            s  += p;
            an += p * vn[j];
            al += p * vl[j];
        }
    }

    // ---- intra-wave merge: even-k state <-> odd-k state (all lanes end up full)
    {
        const float mo = __shfl_xor(m, 32);
        const float so = __shfl_xor(s, 32);
        fx4 ano, alo;
        ano.x = __shfl_xor(an.x, 32); ano.y = __shfl_xor(an.y, 32);
        ano.z = __shfl_xor(an.z, 32); ano.w = __shfl_xor(an.w, 32);
        alo.x = __shfl_xor(al.x, 32); alo.y = __shfl_xor(al.y, 32);
        alo.z = __shfl_xor(al.z, 32); alo.w = __shfl_xor(al.w, 32);
        const float mt = fmaxf(m, mo);
        const float e0 = __expf(m - mt);
        const float e1 = __expf(mo - mt);
        s  = s * e0 + so * e1;
        an = an * e0 + ano * e1;
        al = al * e0 + alo * e1;
        m  = mt;
    }

    // ---- cross-wave merge (k-range halves) via LDS, one barrier
    if (h == 0) s_an[bloc][w][l32] = an; else s_al[bloc][w][l32] = al;
    if (lane == 0) { s_m[bloc][w] = m; s_s[bloc][w] = s; }
    __syncthreads();

    if (w == 0) {
        const float m1 = s_m[bloc][1];
        const float s1 = s_s[bloc][1];
        const fx4 mine  = (h == 0) ? an : al;
        const fx4 other = (h == 0) ? s_an[bloc][1][l32] : s_al[bloc][1][l32];
        const float M   = fmaxf(m, m1);
        const float e0  = __expf(m - M);
        const float e1  = __expf(m1 - M);
        const float inv = 1.0f / (s * e0 + s1 * e1);
        const fx4 r = (mine * e0 + other * e1) * inv;
        if (h == 0)
            __builtin_nontemporal_store(r, &((fx4*)(out + (size_t)b * DD))[l32]);
        else
            __builtin_nontemporal_store(r, &((fx4*)(out + (size_t)BB * DD + (size_t)b * DD))[l32]);
    }
}

extern "C" void kernel_launch(void* const* d_in, const int* in_sizes, int n_in,
                              void* d_out, int out_size, void* d_ws, size_t ws_size,
                              hipStream_t stream) {
    const float* tf   = (const float*)d_in[0];
    const float* nf   = (const float*)d_in[1];
    const float* nl   = (const float*)d_in[2];
    const int*   mask = (const int*)d_in[3];
    const float* W    = (const float*)d_in[4];
    float* out = (float*)d_out;
    float* tgt = (float*)d_ws;                 // B*D*4 = 2 MiB scratch

    target_gemm<<<BB / 8, 512, 0, stream>>>(tf, W, tgt);
    attn_online<<<BB / 2, 256, 0, stream>>>(nf, nl, mask, tgt, out);
}

// Round 11
// 182.512 us; speedup vs baseline: 1.0968x; 1.0968x over previous
//
#include <hip/hip_runtime.h>
#include <math.h>

#define BB   4096
#define KK   200
#define DD   128
#define FDIM 1024
#define MASK_FILL (-4294967295.0f)   // -(2^32)+1, as fp32

typedef float fx4 __attribute__((ext_vector_type(4)));

// ---------------- Kernel 1: target = target_feats @ W^T  ([B,FD] x [D,FD] -> [B,D])
// 512 blocks x 512 threads; 8 batch rows per block; FD split in QUARTERS per
// thread (h = tid>>7 in 0..3) -> 24 waves/CU to hide the W-load L2 latency.
__global__ __launch_bounds__(512) void target_gemm(const float* __restrict__ tf,
                                                   const float* __restrict__ W,
                                                   float* __restrict__ tgt) {
    __shared__ float s_tf[8 * FDIM];        // 32 KiB
    __shared__ float s_red[8][4][DD];       // 16 KiB: per-h partials
    const int tid = threadIdx.x;
    const int d   = tid & 127;
    const int h   = tid >> 7;               // 0..3: which quarter of FD (wave-uniform)
    const size_t r0 = (size_t)blockIdx.x * 8;

    const fx4* src = (const fx4*)(tf + r0 * FDIM);
    for (int i = tid; i < 8 * FDIM / 4; i += 512)
        ((fx4*)s_tf)[i] = src[i];
    __syncthreads();

    float acc[8] = {0, 0, 0, 0, 0, 0, 0, 0};
    const fx4* wr = (const fx4*)(W + (size_t)d * FDIM) + h * (FDIM / 16);
    #pragma unroll 4
    for (int i = 0; i < FDIM / 16; ++i) {   // 64 fx4 chunks of this quarter
        fx4 w = wr[i];
        #pragma unroll
        for (int r = 0; r < 8; ++r) {
            fx4 t = ((const fx4*)(s_tf + r * FDIM + h * (FDIM / 4)))[i];  // wave-broadcast
            acc[r] += w.x * t.x + w.y * t.y + w.z * t.z + w.w * t.w;
        }
    }
    #pragma unroll
    for (int r = 0; r < 8; ++r) s_red[r][h][d] = acc[r];
    __syncthreads();
    if (h == 0) {
        #pragma unroll
        for (int r = 0; r < 8; ++r)
            tgt[(r0 + r) * DD + d] = s_red[r][0][d] + s_red[r][1][d]
                                   + s_red[r][2][d] + s_red[r][3][d];
    }
}

// ---------------- Kernel 2: TWO waves per batch row (k 0..99 / 100..199), one
// pass, online softmax. Within a wave: lanes 0-31 even k, lanes 32-63 odd k.
// Chunks of 2 row-pairs (4 loads in flight) keep VGPR <= 64 so 8 waves/SIMD
// (32 waves/CU) hide HBM latency. Nontemporal loads: read-once streams must
// NOT allocate in L2/LLC (round-10 regression when nt was removed).
__global__ __launch_bounds__(256, 8) void attn_online(const float* __restrict__ nf,
                                                      const float* __restrict__ nl,
                                                      const int*   __restrict__ mask,
                                                      const float* __restrict__ tgt,
                                                      float* __restrict__ out) {
    __shared__ float s_m[2][2], s_s[2][2];
    __shared__ fx4   s_an[2][2][32];     // [bloc][w][col]
    __shared__ fx4   s_al[2][2][32];

    const int tid  = threadIdx.x;
    const int lane = tid & 63;
    const int l32  = lane & 31;          // fx4 column (d = 4*l32)
    const int h    = (lane >> 5) & 1;    // parity half: 0 -> even k, 1 -> odd k
    const int bloc = tid >> 7;           // which of the block's 2 batch rows
    const int b    = __builtin_amdgcn_readfirstlane(blockIdx.x * 2 + bloc);
    const int w    = __builtin_amdgcn_readfirstlane((tid >> 6) & 1);  // k-range half

    const fx4* nf4 = (const fx4*)(nf + (size_t)b * KK * DD) + (size_t)w * 50 * 64;
    const fx4* nl4 = (const fx4*)(nl + (size_t)b * KK * DD) + (size_t)w * 50 * 64;
    const int* mb  = mask + (size_t)b * KK + w * 100;
    const fx4  tg  = ((const fx4*)(tgt + (size_t)b * DD))[l32];

    float m = -INFINITY, s = 0.0f;
    fx4 an = {0, 0, 0, 0}, al = {0, 0, 0, 0};

    for (int c = 0; c < 25; ++c) {       // 25 chunks x 2 pairs (4 k) per wave
        fx4 vn[2], vl[2];
        #pragma unroll
        for (int j = 0; j < 2; ++j) {
            const int idx = (c * 2 + j) * 64 + lane;   // rows 4c+2j+h, col l32
            vn[j] = __builtin_nontemporal_load(nf4 + idx);
            vl[j] = __builtin_nontemporal_load(nl4 + idx);
        }
        float a[2];
        #pragma unroll
        for (int j = 0; j < 2; ++j) {
            float d = vn[j].x * tg.x + vn[j].y * tg.y + vn[j].z * tg.z + vn[j].w * tg.w;
            #pragma unroll
            for (int off = 16; off > 0; off >>= 1)   // stays within 32-lane halves
                d += __shfl_xor(d, off);
            const int k0 = c * 4 + 2 * j;
            const int mk = h ? mb[k0 + 1] : mb[k0];  // scalar loads, vector select
            a[j] = (mk > 0) ? d : MASK_FILL;
        }
        const float mn = fmaxf(m, fmaxf(a[0], a[1]));
        const float r  = __expf(m - mn);             // exp(-inf)=0 on first chunk
        m = mn;
        s *= r; an *= r; al *= r;
        #pragma unroll
        for (int j = 0; j < 2; ++j) {
            const float p = __expf(a[j] - m);        // p <= 1 always
            s  += p;
            an += p * vn[j];
            al += p * vl[j];
        }
    }

    // ---- intra-wave merge: even-k state <-> odd-k state (all lanes end up full)
    {
        const float mo = __shfl_xor(m, 32);
        const float so = __shfl_xor(s, 32);
        fx4 ano, alo;
        ano.x = __shfl_xor(an.x, 32); ano.y = __shfl_xor(an.y, 32);
        ano.z = __shfl_xor(an.z, 32); ano.w = __shfl_xor(an.w, 32);
        alo.x = __shfl_xor(al.x, 32); alo.y = __shfl_xor(al.y, 32);
        alo.z = __shfl_xor(al.z, 32); alo.w = __shfl_xor(al.w, 32);
        const float mt = fmaxf(m, mo);
        const float e0 = __expf(m - mt);
        const float e1 = __expf(mo - mt);
        s  = s * e0 + so * e1;
        an = an * e0 + ano * e1;
        al = al * e0 + alo * e1;
        m  = mt;
    }

    // ---- cross-wave merge (k-range halves) via LDS, one barrier
    if (h == 0) s_an[bloc][w][l32] = an; else s_al[bloc][w][l32] = al;
    if (lane == 0) { s_m[bloc][w] = m; s_s[bloc][w] = s; }
    __syncthreads();

    if (w == 0) {
        const float m1 = s_m[bloc][1];
        const float s1 = s_s[bloc][1];
        const fx4 mine  = (h == 0) ? an : al;
        const fx4 other = (h == 0) ? s_an[bloc][1][l32] : s_al[bloc][1][l32];
        const float M   = fmaxf(m, m1);
        const float e0  = __expf(m - M);
        const float e1  = __expf(m1 - M);
        const float inv = 1.0f / (s * e0 + s1 * e1);
        const fx4 r = (mine * e0 + other * e1) * inv;
        if (h == 0)
            __builtin_nontemporal_store(r, &((fx4*)(out + (size_t)b * DD))[l32]);
        else
            __builtin_nontemporal_store(r, &((fx4*)(out + (size_t)BB * DD + (size_t)b * DD))[l32]);
    }
}

extern "C" void kernel_launch(void* const* d_in, const int* in_sizes, int n_in,
                              void* d_out, int out_size, void* d_ws, size_t ws_size,
                              hipStream_t stream) {
    const float* tf   = (const float*)d_in[0];
    const float* nf   = (const float*)d_in[1];
    const float* nl   = (const float*)d_in[2];
    const int*   mask = (const int*)d_in[3];
    const float* W    = (const float*)d_in[4];
    float* out = (float*)d_out;
    float* tgt = (float*)d_ws;                 // B*D*4 = 2 MiB scratch

    target_gemm<<<BB / 8, 512, 0, stream>>>(tf, W, tgt);
    attn_online<<<BB / 2, 256, 0, stream>>>(nf, nl, mask, tgt, out);
}

// Round 12
// 172.951 us; speedup vs baseline: 1.1575x; 1.0553x over previous
//
#include <hip/hip_runtime.h>
#include <math.h>

#define BB   4096
#define KK   200
#define DD   128
#define FDIM 1024
#define MASK_FILL (-4294967295.0f)   // -(2^32)+1, as fp32

typedef float fx4 __attribute__((ext_vector_type(4)));

__device__ __forceinline__ float red32(float v) {
    #pragma unroll
    for (int off = 16; off > 0; off >>= 1) v += __shfl_xor(v, off);
    return v;
}

// ---------------- Kernel 1: target = target_feats @ W^T  (R9's proven version)
__global__ __launch_bounds__(256) void target_gemm(const float* __restrict__ tf,
                                                   const float* __restrict__ W,
                                                   float* __restrict__ tgt) {
    __shared__ float s_tf[8 * FDIM];        // 32 KiB
    __shared__ float s_red[8][DD];          // 4 KiB
    const int tid = threadIdx.x;
    const int d   = tid & 127;
    const int h   = tid >> 7;               // 0/1: which half of FD (wave-uniform)
    const size_t r0 = (size_t)blockIdx.x * 8;

    const fx4* src = (const fx4*)(tf + r0 * FDIM);
    for (int i = tid; i < 8 * FDIM / 4; i += 256)
        ((fx4*)s_tf)[i] = src[i];
    __syncthreads();

    float acc[8] = {0, 0, 0, 0, 0, 0, 0, 0};
    const fx4* wr = (const fx4*)(W + (size_t)d * FDIM) + h * (FDIM / 8);
    #pragma unroll 4
    for (int i = 0; i < FDIM / 8; ++i) {
        fx4 w = wr[i];
        #pragma unroll
        for (int r = 0; r < 8; ++r) {
            fx4 t = ((const fx4*)(s_tf + r * FDIM + h * (FDIM / 2)))[i];  // wave-broadcast
            acc[r] += w.x * t.x + w.y * t.y + w.z * t.z + w.w * t.w;
        }
    }
    if (h == 1) {
        #pragma unroll
        for (int r = 0; r < 8; ++r) s_red[r][d] = acc[r];
    }
    __syncthreads();
    if (h == 0) {
        #pragma unroll
        for (int r = 0; r < 8; ++r)
            tgt[(r0 + r) * DD + d] = acc[r] + s_red[r][d];
    }
}

// ---------------- Kernel 2: TWO waves per batch row, online softmax, with a
// 1-deep software pipeline: next chunk's 4 nt loads issue BEFORE the current
// chunk's shfl/exp dependency chain, doubling in-flight bytes per wave.
// Named A/B buffers (no runtime-indexed arrays -> no scratch).
__global__ __launch_bounds__(256, 8) void attn_online(const float* __restrict__ nf,
                                                      const float* __restrict__ nl,
                                                      const int*   __restrict__ mask,
                                                      const float* __restrict__ tgt,
                                                      float* __restrict__ out) {
    __shared__ float s_m[2][2], s_s[2][2];
    __shared__ fx4   s_an[2][2][32];     // [bloc][w][col]
    __shared__ fx4   s_al[2][2][32];

    const int tid  = threadIdx.x;
    const int lane = tid & 63;
    const int l32  = lane & 31;          // fx4 column (d = 4*l32)
    const int h    = (lane >> 5) & 1;    // parity half: 0 -> even k, 1 -> odd k
    const int bloc = tid >> 7;           // which of the block's 2 batch rows
    const int b    = __builtin_amdgcn_readfirstlane(blockIdx.x * 2 + bloc);
    const int w    = __builtin_amdgcn_readfirstlane((tid >> 6) & 1);  // k-range half

    const fx4* nf4 = (const fx4*)(nf + (size_t)b * KK * DD) + (size_t)w * 50 * 64;
    const fx4* nl4 = (const fx4*)(nl + (size_t)b * KK * DD) + (size_t)w * 50 * 64;
    const int* mb  = mask + (size_t)b * KK + w * 100;
    const fx4  tg  = ((const fx4*)(tgt + (size_t)b * DD))[l32];

    float m = -INFINITY, s = 0.0f;
    fx4 an = {0, 0, 0, 0}, al = {0, 0, 0, 0};

#define LOADC(N0, N1, L0, L1, c)                                    \
    {                                                               \
        const int base_ = (c) * 128 + lane;                         \
        N0 = __builtin_nontemporal_load(nf4 + base_);               \
        N1 = __builtin_nontemporal_load(nf4 + base_ + 64);          \
        L0 = __builtin_nontemporal_load(nl4 + base_);               \
        L1 = __builtin_nontemporal_load(nl4 + base_ + 64);          \
    }

#define COMPC(N0, N1, L0, L1, c)                                             \
    {                                                                        \
        float a0 = red32(N0.x * tg.x + N0.y * tg.y + N0.z * tg.z + N0.w * tg.w); \
        float a1 = red32(N1.x * tg.x + N1.y * tg.y + N1.z * tg.z + N1.w * tg.w); \
        const int k0_ = (c) * 4;                                             \
        const int mA_ = h ? mb[k0_ + 1] : mb[k0_];                           \
        const int mB_ = h ? mb[k0_ + 3] : mb[k0_ + 2];                       \
        a0 = (mA_ > 0) ? a0 : MASK_FILL;                                     \
        a1 = (mB_ > 0) ? a1 : MASK_FILL;                                     \
        const float mn_ = fmaxf(m, fmaxf(a0, a1));                           \
        const float r_  = __expf(m - mn_);                                   \
        m = mn_;                                                             \
        s *= r_; an *= r_; al *= r_;                                         \
        const float p0_ = __expf(a0 - m);                                    \
        const float p1_ = __expf(a1 - m);                                    \
        s += p0_ + p1_;                                                      \
        an += p0_ * N0 + p1_ * N1;                                           \
        al += p0_ * L0 + p1_ * L1;                                           \
    }

    fx4 nA0, nA1, lA0, lA1, nB0, nB1, lB0, lB1;
    LOADC(nA0, nA1, lA0, lA1, 0)
    for (int c = 0; c < 24; c += 2) {
        LOADC(nB0, nB1, lB0, lB1, c + 1)
        COMPC(nA0, nA1, lA0, lA1, c)
        LOADC(nA0, nA1, lA0, lA1, c + 2)     // c <= 22 -> chunk <= 24: in range
        COMPC(nB0, nB1, lB0, lB1, c + 1)
    }
    COMPC(nA0, nA1, lA0, lA1, 24)            // last chunk, loaded in final iter

#undef LOADC
#undef COMPC

    // ---- intra-wave merge: even-k state <-> odd-k state (all lanes end up full)
    {
        const float mo = __shfl_xor(m, 32);
        const float so = __shfl_xor(s, 32);
        fx4 ano, alo;
        ano.x = __shfl_xor(an.x, 32); ano.y = __shfl_xor(an.y, 32);
        ano.z = __shfl_xor(an.z, 32); ano.w = __shfl_xor(an.w, 32);
        alo.x = __shfl_xor(al.x, 32); alo.y = __shfl_xor(al.y, 32);
        alo.z = __shfl_xor(al.z, 32); alo.w = __shfl_xor(al.w, 32);
        const float mt = fmaxf(m, mo);
        const float e0 = __expf(m - mt);
        const float e1 = __expf(mo - mt);
        s  = s * e0 + so * e1;
        an = an * e0 + ano * e1;
        al = al * e0 + alo * e1;
        m  = mt;
    }

    // ---- cross-wave merge (k-range halves) via LDS, one barrier
    if (h == 0) s_an[bloc][w][l32] = an; else s_al[bloc][w][l32] = al;
    if (lane == 0) { s_m[bloc][w] = m; s_s[bloc][w] = s; }
    __syncthreads();

    if (w == 0) {
        const float m1 = s_m[bloc][1];
        const float s1 = s_s[bloc][1];
        const fx4 mine  = (h == 0) ? an : al;
        const fx4 other = (h == 0) ? s_an[bloc][1][l32] : s_al[bloc][1][l32];
        const float M   = fmaxf(m, m1);
        const float e0  = __expf(m - M);
        const float e1  = __expf(m1 - M);
        const float inv = 1.0f / (s * e0 + s1 * e1);
        const fx4 r = (mine * e0 + other * e1) * inv;
        if (h == 0)
            __builtin_nontemporal_store(r, &((fx4*)(out + (size_t)b * DD))[l32]);
        else
            __builtin_nontemporal_store(r, &((fx4*)(out + (size_t)BB * DD + (size_t)b * DD))[l32]);
    }
}

extern "C" void kernel_launch(void* const* d_in, const int* in_sizes, int n_in,
                              void* d_out, int out_size, void* d_ws, size_t ws_size,
                              hipStream_t stream) {
    const float* tf   = (const float*)d_in[0];
    const float* nf   = (const float*)d_in[1];
    const float* nl   = (const float*)d_in[2];
    const int*   mask = (const int*)d_in[3];
    const float* W    = (const float*)d_in[4];
    float* out = (float*)d_out;
    float* tgt = (float*)d_ws;                 // B*D*4 = 2 MiB scratch

    target_gemm<<<BB / 8, 256, 0, stream>>>(tf, W, tgt);
    attn_online<<<BB / 2, 256, 0, stream>>>(nf, nl, mask, tgt, out);
}